// Round 6
// baseline (240.502 us; speedup 1.0000x reference)
//
#include <hip/hip_runtime.h>
#include <hip/hip_bf16.h>

// Segment-mean over N=2,000,000 sorted nodes -> G=16384 graphs, then linear.
// x: [N,64] f32, segment_ids: [N] int32 (sorted), weight: [128,64] f32,
// bias: [128] f32, out: [G,128] f32.  HBM-bound: ~520 MB read -> ~84 us floor.
//
// R6: R3's proven fused kernel (windowed search + branch-free float4 stream +
// LDS-W epilogue) with PERSISTENT blocks + work-stealing over graphs:
//   - grid = 1024 blocks x 512 thr = 4 blocks/CU exactly (single cohort)
//   - wave w takes graph w statically, then steals via atomicAdd ticket
//   - 16-row main loop (4 independent float4 accs, 4 KiB in flight/wave)
// Output is deterministic: each graph is summed by one wave in fixed row
// order; values don't depend on the wave<->graph mapping.

#define IN_CH 64
#define OUT_CH 128
#define FBLK 512
#define FGRID 1024          // 4 blocks/CU x 256 CU -> all resident

typedef float f32x4 __attribute__((ext_vector_type(4)));

__device__ __forceinline__ f32x4 ntload(const float* p) {
    return __builtin_nontemporal_load(reinterpret_cast<const f32x4*>(p));
}

// Branch-free stream of rows [s0,s1); afterwards every lane holds the full
// segment sum of its channel quad [cq, cq+3].
__device__ __forceinline__ void stream_seg(const float* __restrict__ x,
                                           int s0, int s1, int rs, int cq,
                                           float& sx, float& sy,
                                           float& sz, float& sw) {
    f32x4 a0 = {0.f, 0.f, 0.f, 0.f};
    f32x4 a1 = {0.f, 0.f, 0.f, 0.f};
    f32x4 a2 = {0.f, 0.f, 0.f, 0.f};
    f32x4 a3 = {0.f, 0.f, 0.f, 0.f};
    int r = s0;
    for (; r + 16 <= s1; r += 16) {        // 4 KiB in flight per wave
        const f32x4 v0 = ntload(x + (size_t)(r + rs)      * IN_CH + cq);
        const f32x4 v1 = ntload(x + (size_t)(r + 4 + rs)  * IN_CH + cq);
        const f32x4 v2 = ntload(x + (size_t)(r + 8 + rs)  * IN_CH + cq);
        const f32x4 v3 = ntload(x + (size_t)(r + 12 + rs) * IN_CH + cq);
        a0 += v0; a1 += v1; a2 += v2; a3 += v3;
    }
    for (; r + 4 <= s1; r += 4) {          // up to 3 quad steps
        a0 += ntload(x + (size_t)(r + rs) * IN_CH + cq);
    }
    if (r + rs < s1) {                     // ragged tail (predicated)
        a1 += ntload(x + (size_t)(r + rs) * IN_CH + cq);
    }
    const f32x4 a = (a0 + a1) + (a2 + a3);
    sx = a.x; sy = a.y; sz = a.z; sw = a.w;
    sx += __shfl_xor(sx, 16); sy += __shfl_xor(sy, 16);
    sz += __shfl_xor(sz, 16); sw += __shfl_xor(sw, 16);
    sx += __shfl_xor(sx, 32); sy += __shfl_xor(sy, 32);
    sz += __shfl_xor(sz, 32); sw += __shfl_xor(sw, 32);
}

__global__ __launch_bounds__(FBLK) void fused_steal_kernel(
        const float* __restrict__ x, const int* __restrict__ ids,
        const float* __restrict__ W, const float* __restrict__ bias,
        float* __restrict__ out, int* __restrict__ counter, int N, int G) {
    // W transposed: w_lds[c*129 + o] = W[o][c]; stride 129 -> writes 2-way
    // (free) and epilogue reads conflict-free.
    __shared__ float w_lds[IN_CH * 129];
    const int t = threadIdx.x;
    for (int i = t; i < OUT_CH * IN_CH; i += FBLK) {
        const int o = i >> 6, c = i & 63;
        w_lds[c * 129 + o] = W[i];
    }
    __syncthreads();

    const int wv = t >> 6, l = t & 63;
    const int nwaves = FGRID * (FBLK / 64);     // 8192
    int g = blockIdx.x * (FBLK / 64) + wv;      // static first graph

    const int rs = l >> 4;               // row stream 0..3
    const int cq = (l & 15) << 2;        // channel quad base
    const float b0 = bias[l], b1 = bias[l + 64];

    while (g < G) {
        // ---- windowed binary search: lanes 0/1 find lower_bound(g), (g+1);
        // validated +-4096 window with full-range fallback -> correct for any
        // sorted input.
        const int tgt = g + (l & 1);
        int lo = 0, hi = N;
        {
            const int guess = (int)(((long long)tgt * (long long)N) / (long long)G);
            int wlo = guess - 4096; if (wlo < 0) wlo = 0;
            int whi = guess + 4096; if (whi > N) whi = N;
            const bool ok_lo = (wlo == 0) || (ids[wlo - 1] < tgt);
            const bool ok_hi = (whi == N) || (ids[whi] >= tgt);
            if (ok_lo && ok_hi) { lo = wlo; hi = whi; }
            while (lo < hi) {
                const int mid = (lo + hi) >> 1;
                if (ids[mid] < tgt) lo = mid + 1; else hi = mid;
            }
        }
        const int s0 = __shfl(lo, 0);
        const int s1 = __shfl(lo, 1);

        // ---- stream + reduce
        float sx, sy, sz, sw;
        stream_seg(x, s0, s1, rs, cq, sx, sy, sz, sw);
        const float cnt = (float)(s1 - s0);
        const float m0 = sx / cnt, m1 = sy / cnt;
        const float m2 = sz / cnt, m3 = sw / cnt;

        // ---- epilogue: out[g][l], out[g][l+64]; mean channel c in lane
        // (c>>2) component (c&3); compile-time-lane __shfl -> v_readlane.
        float o0 = b0, o1 = b1;
        #pragma unroll
        for (int c = 0; c < IN_CH; ++c) {
            float m;
            switch (c & 3) {
                case 0:  m = __shfl(m0, c >> 2); break;
                case 1:  m = __shfl(m1, c >> 2); break;
                case 2:  m = __shfl(m2, c >> 2); break;
                default: m = __shfl(m3, c >> 2); break;
            }
            o0 = fmaf(w_lds[c * 129 + l],      m, o0);
            o1 = fmaf(w_lds[c * 129 + l + 64], m, o1);
        }
        out[(size_t)g * OUT_CH + l]      = o0;
        out[(size_t)g * OUT_CH + l + 64] = o1;

        // ---- steal next graph
        int tk = 0;
        if (l == 0) tk = atomicAdd(counter, 1);
        tk = __shfl(tk, 0);
        g = nwaves + tk;
    }
}

// ---- Fallback (R3 static fused kernel) if ws can't even hold the counter.
#define WPB 8
#define BLOCK (WPB * 64)
__global__ __launch_bounds__(BLOCK) void fused_pool_linear_kernel(
        const float* __restrict__ x, const int* __restrict__ ids,
        const float* __restrict__ W, const float* __restrict__ bias,
        float* __restrict__ out, int N, int G) {
    __shared__ float w_lds[IN_CH * 129];
    const int t  = threadIdx.x;
    const int wv = t >> 6;
    const int l  = t & 63;
    const int g  = blockIdx.x * WPB + wv;

    int s0 = 0, s1 = 0;
    if (g < G) {
        const int target = g + (l & 1);
        int lo = 0, hi = N;
        const int guess = (int)(((long long)target * (long long)N) / (long long)G);
        int wlo = guess - 4096; if (wlo < 0) wlo = 0;
        int whi = guess + 4096; if (whi > N) whi = N;
        const bool ok_lo = (wlo == 0) || (ids[wlo - 1] < target);
        const bool ok_hi = (whi == N) || (ids[whi] >= target);
        if (ok_lo && ok_hi) { lo = wlo; hi = whi; }
        while (lo < hi) {
            const int mid = (lo + hi) >> 1;
            if (ids[mid] < target) lo = mid + 1; else hi = mid;
        }
        s0 = __shfl(lo, 0);
        s1 = __shfl(lo, 1);
    }
    for (int i = t; i < OUT_CH * IN_CH; i += BLOCK) {
        const int o = i >> 6, c = i & 63;
        w_lds[c * 129 + o] = W[i];
    }
    __syncthreads();
    if (g >= G) return;

    const int rs = l >> 4;
    const int cq = (l & 15) << 2;
    float sx, sy, sz, sw;
    stream_seg(x, s0, s1, rs, cq, sx, sy, sz, sw);
    const float cnt = (float)(s1 - s0);
    const float m0 = sx / cnt, m1 = sy / cnt, m2 = sz / cnt, m3 = sw / cnt;
    float o0 = bias[l], o1 = bias[l + 64];
    #pragma unroll
    for (int c = 0; c < IN_CH; ++c) {
        float m;
        switch (c & 3) {
            case 0:  m = __shfl(m0, c >> 2); break;
            case 1:  m = __shfl(m1, c >> 2); break;
            case 2:  m = __shfl(m2, c >> 2); break;
            default: m = __shfl(m3, c >> 2); break;
        }
        o0 = fmaf(w_lds[c * 129 + l],      m, o0);
        o1 = fmaf(w_lds[c * 129 + l + 64], m, o1);
    }
    out[(size_t)g * OUT_CH + l]      = o0;
    out[(size_t)g * OUT_CH + l + 64] = o1;
}

extern "C" void kernel_launch(void* const* d_in, const int* in_sizes, int n_in,
                              void* d_out, int out_size, void* d_ws, size_t ws_size,
                              hipStream_t stream) {
    const float* x    = (const float*)d_in[0];
    const int*   ids  = (const int*)d_in[1];
    const float* W    = (const float*)d_in[2];
    const float* bias = (const float*)d_in[3];
    float* out = (float*)d_out;

    const int N = in_sizes[1];             // 2,000,000
    const int G = out_size / OUT_CH;       // 16384

    if (ws_size >= sizeof(int)) {
        int* counter = (int*)d_ws;
        hipMemsetAsync(counter, 0, sizeof(int), stream);   // re-zero per launch
        fused_steal_kernel<<<FGRID, FBLK, 0, stream>>>(
            x, ids, W, bias, out, counter, N, G);
    } else {
        const int blocks = (G + WPB - 1) / WPB;
        fused_pool_linear_kernel<<<blocks, BLOCK, 0, stream>>>(
            x, ids, W, bias, out, N, G);
    }
}

// Round 7
// 133.725 us; speedup vs baseline: 1.7985x; 1.7985x over previous
//
#include <hip/hip_runtime.h>
#include <hip/hip_bf16.h>

// Segment-mean over N=2,000,000 sorted nodes -> G=16384 graphs, then linear.
// x: [N,64] f32, segment_ids: [N] int32 (sorted), weight: [128,64] f32,
// bias: [128] f32, out: [G,128] f32.  HBM-bound: ~520 MB read -> ~84 us floor.
//
// R7: equal-rows phase A. Each wave owns 256 contiguous rows; run boundaries
// come from ONE coalesced id read + __ballot transition masks (no id loads,
// no branches in the stream). Runs use the proven branch-free float4 stream;
// partial sums flush via wave-uniform atomics into sums[G][64]/counts[G].
// Phase B: mean + linear (proven). Lessons: R4 (ids in stream = serialization),
// R5 (launch_bounds min-waves = spills), R6 (persistent loop = reg bloat).

#define IN_CH 64
#define OUT_CH 128
#define RPW 256              // rows per wave (chunk), multiple of 4
#define ABLK 256             // phase A block: 4 waves, no LDS
#define LBLK 512             // phase B block: 8 waves
#define LGRID 512            // phase B grid

typedef float f32x4 __attribute__((ext_vector_type(4)));

__device__ __forceinline__ f32x4 ntload(const float* p) {
    return __builtin_nontemporal_load(reinterpret_cast<const f32x4*>(p));
}

// Branch-free stream of rows [s0,s1); afterwards every lane holds the full
// run sum of its channel quad [cq, cq+3].
__device__ __forceinline__ void stream_seg(const float* __restrict__ x,
                                           int s0, int s1, int rs, int cq,
                                           float& sx, float& sy,
                                           float& sz, float& sw) {
    f32x4 a0 = {0.f, 0.f, 0.f, 0.f};
    f32x4 a1 = {0.f, 0.f, 0.f, 0.f};
    int r = s0;
    for (; r + 8 <= s1; r += 8) {
        const f32x4 v0 = ntload(x + (size_t)(r + rs)     * IN_CH + cq);
        const f32x4 v1 = ntload(x + (size_t)(r + 4 + rs) * IN_CH + cq);
        a0 += v0; a1 += v1;
    }
    if (r + 4 <= s1) {
        a0 += ntload(x + (size_t)(r + rs) * IN_CH + cq);
        r += 4;
    }
    if (r + rs < s1) {
        a1 += ntload(x + (size_t)(r + rs) * IN_CH + cq);
    }
    const f32x4 a = a0 + a1;
    sx = a.x; sy = a.y; sz = a.z; sw = a.w;
    sx += __shfl_xor(sx, 16); sy += __shfl_xor(sy, 16);
    sz += __shfl_xor(sz, 16); sw += __shfl_xor(sw, 16);
    sx += __shfl_xor(sx, 32); sy += __shfl_xor(sy, 32);
    sz += __shfl_xor(sz, 32); sw += __shfl_xor(sw, 32);
}

__device__ __forceinline__ void flush_run(float* __restrict__ sums,
                                          int* __restrict__ counts,
                                          int g, int l, int cq, int len,
                                          float sx, float sy, float sz, float sw) {
    if (l < 16) {
        float* p = sums + (size_t)g * IN_CH + cq;
        atomicAdd(p + 0, sx);
        atomicAdd(p + 1, sy);
        atomicAdd(p + 2, sz);
        atomicAdd(p + 3, sw);
    }
    if (l == 0) atomicAdd(counts + g, len);
}

// Phase A: equal-rows chunks, ballot-based run detection, branch-free streams.
__global__ __launch_bounds__(ABLK) void seg_accum_kernel(
        const float* __restrict__ x, const int* __restrict__ ids,
        float* __restrict__ sums, int* __restrict__ counts, int N) {
    const int t = threadIdx.x;
    const int w = blockIdx.x * (ABLK / 64) + (t >> 6);
    const int l = t & 63;
    const int row0 = w * RPW;
    if (row0 >= N) return;
    const int row_end = (row0 + RPW < N) ? row0 + RPW : N;

    const int rs = l >> 4;              // row stream 0..3
    const int cq = (l & 15) << 2;       // channel quad base

    // One coalesced id read for the whole chunk: idv[k] = ids[row0 + 64k + l].
    int idv[4];
    #pragma unroll
    for (int k = 0; k < 4; ++k) {
        const int p = row0 + 64 * k + l;
        idv[k] = ids[p < N ? p : (N - 1)];
    }

    // Transition masks: bit l of tm[k] set iff ids[p] != ids[p-1], p inside chunk.
    unsigned long long tm[4];
    #pragma unroll
    for (int k = 0; k < 4; ++k) {
        int prev = __shfl_up(idv[k], 1);            // lane0 -> own value
        if (k > 0 && l == 0) prev = __shfl(idv[k - 1], 63);
        const int p = row0 + 64 * k + l;
        const bool tr = (p > row0) && (p < row_end) && (idv[k] != prev);
        tm[k] = __ballot(tr);
    }

    // Iterate runs (wave-uniform; avg 2-3 per chunk). Stream each branch-free.
    int run_start = row0;
    int g = __shfl(idv[0], 0);                      // ids[row0]
    float sx, sy, sz, sw;
    #pragma unroll
    for (int k = 0; k < 4; ++k) {
        unsigned long long m = tm[k];
        while (m) {
            const int b = __builtin_ctzll(m);
            m &= m - 1;
            const int pos = row0 + 64 * k + b;      // run boundary
            stream_seg(x, run_start, pos, rs, cq, sx, sy, sz, sw);
            flush_run(sums, counts, g, l, cq, pos - run_start, sx, sy, sz, sw);
            run_start = pos;
            g = __shfl(idv[k], b);                  // ids[pos]
        }
    }
    stream_seg(x, run_start, row_end, rs, cq, sx, sy, sz, sw);
    flush_run(sums, counts, g, l, cq, row_end - run_start, sx, sy, sz, sw);
}

// Phase B: mean + linear. W transposed in LDS (stride 129, conflict-free).
__global__ __launch_bounds__(LBLK) void mean_linear_kernel(
        const float* __restrict__ sums, const int* __restrict__ counts,
        const float* __restrict__ W, const float* __restrict__ bias,
        float* __restrict__ out, int G) {
    __shared__ float w_lds[IN_CH * 129];   // w_lds[c*129+o] = W[o][c]
    const int t = threadIdx.x;
    for (int i = t; i < OUT_CH * IN_CH; i += LBLK) {
        const int o = i >> 6, c = i & 63;
        w_lds[c * 129 + o] = W[i];
    }
    __syncthreads();

    const int wv = t >> 6, l = t & 63;
    const int cq = (l & 15) << 2;
    const float b0 = bias[l], b1 = bias[l + 64];

    for (int g = blockIdx.x * (LBLK / 64) + wv; g < G; g += LGRID * (LBLK / 64)) {
        const float cnt = (float)counts[g];
        const f32x4 s = *reinterpret_cast<const f32x4*>(
            sums + (size_t)g * IN_CH + cq);
        const float m0 = s.x / cnt, m1 = s.y / cnt;
        const float m2 = s.z / cnt, m3 = s.w / cnt;

        float o0 = b0, o1 = b1;
        #pragma unroll
        for (int c = 0; c < IN_CH; ++c) {
            float m;
            switch (c & 3) {
                case 0:  m = __shfl(m0, c >> 2); break;
                case 1:  m = __shfl(m1, c >> 2); break;
                case 2:  m = __shfl(m2, c >> 2); break;
                default: m = __shfl(m3, c >> 2); break;
            }
            o0 = fmaf(w_lds[c * 129 + l],      m, o0);
            o1 = fmaf(w_lds[c * 129 + l + 64], m, o1);
        }
        out[(size_t)g * OUT_CH + l]      = o0;
        out[(size_t)g * OUT_CH + l + 64] = o1;
    }
}

// ---- Fallback (R3 fused kernel, proven 100.3 us) if ws too small.
#define WPB 8
#define BLOCK (WPB * 64)
__global__ __launch_bounds__(BLOCK) void fused_pool_linear_kernel(
        const float* __restrict__ x, const int* __restrict__ ids,
        const float* __restrict__ W, const float* __restrict__ bias,
        float* __restrict__ out, int N, int G) {
    __shared__ float w_lds[IN_CH * 129];
    const int t  = threadIdx.x;
    const int wv = t >> 6;
    const int l  = t & 63;
    const int g  = blockIdx.x * WPB + wv;

    int s0 = 0, s1 = 0;
    if (g < G) {
        const int target = g + (l & 1);
        int lo = 0, hi = N;
        const int guess = (int)(((long long)target * (long long)N) / (long long)G);
        int wlo = guess - 4096; if (wlo < 0) wlo = 0;
        int whi = guess + 4096; if (whi > N) whi = N;
        const bool ok_lo = (wlo == 0) || (ids[wlo - 1] < target);
        const bool ok_hi = (whi == N) || (ids[whi] >= target);
        if (ok_lo && ok_hi) { lo = wlo; hi = whi; }
        while (lo < hi) {
            const int mid = (lo + hi) >> 1;
            if (ids[mid] < target) lo = mid + 1; else hi = mid;
        }
        s0 = __shfl(lo, 0);
        s1 = __shfl(lo, 1);
    }
    for (int i = t; i < OUT_CH * IN_CH; i += BLOCK) {
        const int o = i >> 6, c = i & 63;
        w_lds[c * 129 + o] = W[i];
    }
    __syncthreads();
    if (g >= G) return;

    const int rs = l >> 4;
    const int cq = (l & 15) << 2;
    float sx, sy, sz, sw;
    stream_seg(x, s0, s1, rs, cq, sx, sy, sz, sw);
    const float cnt = (float)(s1 - s0);
    const float m0 = sx / cnt, m1 = sy / cnt, m2 = sz / cnt, m3 = sw / cnt;
    float o0 = bias[l], o1 = bias[l + 64];
    #pragma unroll
    for (int c = 0; c < IN_CH; ++c) {
        float m;
        switch (c & 3) {
            case 0:  m = __shfl(m0, c >> 2); break;
            case 1:  m = __shfl(m1, c >> 2); break;
            case 2:  m = __shfl(m2, c >> 2); break;
            default: m = __shfl(m3, c >> 2); break;
        }
        o0 = fmaf(w_lds[c * 129 + l],      m, o0);
        o1 = fmaf(w_lds[c * 129 + l + 64], m, o1);
    }
    out[(size_t)g * OUT_CH + l]      = o0;
    out[(size_t)g * OUT_CH + l + 64] = o1;
}

extern "C" void kernel_launch(void* const* d_in, const int* in_sizes, int n_in,
                              void* d_out, int out_size, void* d_ws, size_t ws_size,
                              hipStream_t stream) {
    const float* x    = (const float*)d_in[0];
    const int*   ids  = (const int*)d_in[1];
    const float* W    = (const float*)d_in[2];
    const float* bias = (const float*)d_in[3];
    float* out = (float*)d_out;

    const int N = in_sizes[1];             // 2,000,000
    const int G = out_size / OUT_CH;       // 16384

    const size_t sums_bytes = (size_t)G * IN_CH * sizeof(float);
    const size_t need = sums_bytes + (size_t)G * sizeof(int);

    if (ws_size >= need) {
        float* sums   = (float*)d_ws;
        int*   counts = (int*)((char*)d_ws + sums_bytes);
        hipMemsetAsync(d_ws, 0, need, stream);
        const int waves   = (N + RPW - 1) / RPW;                      // 7813
        const int ablocks = (waves + (ABLK / 64) - 1) / (ABLK / 64);  // 1954
        seg_accum_kernel<<<ablocks, ABLK, 0, stream>>>(x, ids, sums, counts, N);
        mean_linear_kernel<<<LGRID, LBLK, 0, stream>>>(sums, counts, W, bias, out, G);
    } else {
        const int blocks = (G + WPB - 1) / WPB;
        fused_pool_linear_kernel<<<blocks, BLOCK, 0, stream>>>(
            x, ids, W, bias, out, N, G);
    }
}